// Round 4
// baseline (26431.079 us; speedup 1.0000x reference)
//
#include <hip/hip_runtime.h>
#include <stdint.h>

typedef unsigned short u16;
typedef short v8s __attribute__((ext_vector_type(8)));
typedef float v4f __attribute__((ext_vector_type(4)));

#define B_ 64
#define S_ 1024
#define IN_ 256
#define H_ 512
#define OUT_ 256
#define BS_ (B_ * S_)                 // 65536
#define GS_ ((size_t)BS_ * H_)        // elems per gate buffer
#define NSLAB_ 16
#define NGRP_ 4
#define HP_ (H_ + 8)                  // padded LDS row (u16 elems)

static __device__ __forceinline__ u16 f2bf(float f) {
  uint32_t u = __float_as_uint(f);
  u += 0x7FFFu + ((u >> 16) & 1u);   // round-to-nearest-even
  return (u16)(u >> 16);
}
static __device__ __forceinline__ float bf2f(u16 h) {
  return __uint_as_float(((uint32_t)h) << 16);
}
static __device__ __forceinline__ v4f mfma16(v8s a, v8s b, v4f c) {
  return __builtin_amdgcn_mfma_f32_16x16x32_bf16(a, b, c, 0, 0, 0);
}
// Coherent (agent-scope, relaxed) accesses: served at the coherence point;
// no fences, no L2 invalidate/writeback.
static __device__ __forceinline__ uint64_t cload64(const uint64_t* p) {
  return __hip_atomic_load(p, __ATOMIC_RELAXED, __HIP_MEMORY_SCOPE_AGENT);
}
static __device__ __forceinline__ void cstore32(uint32_t* p, uint32_t v) {
  __hip_atomic_store(p, v, __ATOMIC_RELAXED, __HIP_MEMORY_SCOPE_AGENT);
}

// ---------------------------------------------------------------- utilities
__global__ void cast_input_kernel(const float* __restrict__ src,
                                  u16* __restrict__ dst, int n4) {
  int i = blockIdx.x * blockDim.x + threadIdx.x;
  int stride = gridDim.x * blockDim.x;
  for (; i < n4; i += stride) {
    float4 v = ((const float4*)src)[i];
    uint32_t lo = (uint32_t)f2bf(v.x) | ((uint32_t)f2bf(v.y) << 16);
    uint32_t hi = (uint32_t)f2bf(v.z) | ((uint32_t)f2bf(v.w) << 16);
    ((uint2*)dst)[i] = make_uint2(lo, hi);
  }
}

// dst[n*K + k] = bf16(src[k*N + n])   (transpose + cast)
__global__ void pack_transpose_kernel(const float* __restrict__ src,
                                      u16* __restrict__ dst, int K, int N) {
  int i = blockIdx.x * blockDim.x + threadIdx.x;
  int total = K * N;
  int stride = gridDim.x * blockDim.x;
  for (; i < total; i += stride) {
    int n = i / K, k = i - n * K;
    dst[i] = f2bf(src[(size_t)k * N + n]);
  }
}

// ---------------------------------------------------------------- GEMM
// C[M x N] = A[M x K] * Bt[N x K]^T ; 64x64 block tile, 4 waves of 32x32.
// mode 0: bf16 out split into 3 gate buffers of [BS_][H_] (N = 1536)
// mode 1: f32 out with bias (N = OUT_)
__global__ void __launch_bounds__(256) gemm_kernel(
    const u16* __restrict__ A, const u16* __restrict__ Bt, int N, int K,
    u16* __restrict__ outb, float* __restrict__ outf,
    const float* __restrict__ bias, int mode) {
  const int bn = blockIdx.x * 64;
  const int bm = blockIdx.y * 64;
  const int w = threadIdx.x >> 6;
  const int lane = threadIdx.x & 63;
  const int wm = (w >> 1) * 32, wn = (w & 1) * 32;
  const int fr = lane & 15;
  const int kb = (lane >> 4) * 8;
  v4f acc00 = {0,0,0,0}, acc01 = {0,0,0,0}, acc10 = {0,0,0,0}, acc11 = {0,0,0,0};
  const u16* a0p = A + (size_t)(bm + wm + fr) * K + kb;
  const u16* a1p = a0p + (size_t)16 * K;
  const u16* b0p = Bt + (size_t)(bn + wn + fr) * K + kb;
  const u16* b1p = b0p + (size_t)16 * K;
  for (int kk = 0; kk < K; kk += 32) {
    v8s a0 = *(const v8s*)(a0p + kk);
    v8s a1 = *(const v8s*)(a1p + kk);
    v8s b0 = *(const v8s*)(b0p + kk);
    v8s b1 = *(const v8s*)(b1p + kk);
    acc00 = mfma16(a0, b0, acc00);
    acc01 = mfma16(a0, b1, acc01);
    acc10 = mfma16(a1, b0, acc10);
    acc11 = mfma16(a1, b1, acc11);
  }
  v4f accs[2][2] = {{acc00, acc01}, {acc10, acc11}};
  const int rb = (lane >> 4) * 4;
#pragma unroll
  for (int mi = 0; mi < 2; ++mi)
#pragma unroll
    for (int ni = 0; ni < 2; ++ni)
#pragma unroll
      for (int j = 0; j < 4; ++j) {
        int row = bm + wm + mi * 16 + rb + j;
        int col = bn + wn + ni * 16 + fr;
        float v = accs[mi][ni][j];
        if (mode == 0) {
          int gate = col >> 9, c = col & (H_ - 1);
          outb[(size_t)gate * GS_ + (size_t)row * H_ + c] = f2bf(v);
        } else {
          outf[(size_t)row * N + col] = v + bias[col];
        }
      }
}

// ---------------------------------------------------------------- GRU scan
// 64 WGs = 4 batch-groups (16 rows) x 16 column-slabs (32 cols).
// Recurrent weight slabs live in LDS for all 1024 steps. h / hr are
// exchanged as TAGGED u32 words ((bf16<<16)|tag, tag=(layer<<15)|(t+1))
// through relaxed agent-scope atomics. No flags, no fences: readers poll
// the data itself; a u64 atomic load covers 2 tagged words consistently.
// Anti-dependency safety: a writer reaches the overwrite of hbuf(tag t+1)
// only after staging all slabs' hr(t), which proves every slab has consumed
// h(t-1). Buffers are zeroed at launch start (tags also differ per layer).
// NOTE: xproj and seqout may alias for layer 1 -> no __restrict__ on them.
__global__ void __launch_bounds__(256, 1) gru_scan_kernel(
    const u16* xproj,                // [3][BS_][H_] bf16 (z,r,g)
    const u16* __restrict__ Wht,     // [3][H_][H_] bf16, Wt[g][n][k] = W[k][n]
    const float* __restrict__ bz, const float* __restrict__ br,
    const float* __restrict__ bg,
    const float* __restrict__ hs,    // [B_][2][H_] f32 initial state
    int layer,
    uint32_t* hT,                    // [NGRP_][16][512] tagged u32 exchange
    uint32_t* hrT,                   // [NGRP_][16][512] tagged u32 exchange
    u16* seqout,                     // [B_][S_][H_] bf16
    float* __restrict__ hfinal) {    // [B_][H_] f32 (d_out tail slice)
  __shared__ __align__(16) u16 ldsW[3][32][HP_];  // 99,840 B
  __shared__ __align__(16) u16 ldsX[16][HP_];     // 16,640 B (h / hr staging)
  __shared__ float h32[16][32];                   //  2,048 B (own-col f32 h)
  const int grp = blockIdx.x & (NGRP_ - 1);
  const int slab = blockIdx.x >> 2;
  const int j0 = slab * 32;
  const int tid = threadIdx.x;
  const int gb = grp * 16;          // batch row base of this group

  // stage weight slabs (once)
  for (int idx = tid; idx < 3 * 32 * 64; idx += 256) {
    int gate = idx >> 11;
    int rem = idx & 2047;
    int cl = rem >> 6;
    int kc = (rem & 63) * 8;
    *(v8s*)&ldsW[gate][cl][kc] =
        *(const v8s*)(Wht + ((size_t)gate * H_ + (j0 + cl)) * H_ + kc);
  }
  // h0 init: bf16 full block + f32 own columns
  for (int i = tid; i < 16 * H_; i += 256) {
    int row = i >> 9, col = i & (H_ - 1);
    ldsX[row][col] = f2bf(hs[((size_t)(gb + row) * 2 + layer) * H_ + col]);
  }
  for (int i = tid; i < 16 * 32; i += 256) {
    int row = i >> 5, cl = i & 31;
    h32[row][cl] = hs[((size_t)(gb + row) * 2 + layer) * H_ + j0 + cl];
  }
  __syncthreads();

  const int w = tid >> 6, lane = tid & 63;
  const int fr = lane & 15;
  const int kb = (lane >> 4) * 8;
  const int rb = (lane >> 4) * 4;
  const int nt = w & 1;             // N-tile within slab
  const int gateA = w >> 1;         // waves 0,1 -> z ; waves 2,3 -> r
  const int colL = nt * 16 + fr;
  const int gcol = j0 + colL;
  const float biasA = (gateA == 0) ? bz[gcol] : br[gcol];
  const float biasG = bg[gcol];

  uint32_t* hTg = hT + (size_t)grp * 16 * 512;
  uint32_t* hrTg = hrT + (size_t)grp * 16 * 512;
  const u16* xA = xproj + (size_t)gateA * GS_;
  const u16* xG = xproj + (size_t)2 * GS_;
  const u16* wA = &ldsW[gateA][colL][0];
  const u16* wG = &ldsW[2][colL][0];
  const uint32_t tbase = (uint32_t)(layer & 1) << 15;

  // cooperative staging: poll tagged u64 words, strip tags into ldsX
  auto stage16 = [&](const uint32_t* bufg, uint32_t tag) {
    const uint64_t* src = (const uint64_t*)bufg;
    const uint64_t tagpat = (uint64_t)tag * 0x0000000100000001ull;
    uint64_t q[16];
#pragma unroll
    for (int i = 0; i < 16; ++i) q[i] = cload64(src + i * 256 + tid);
#pragma unroll
    for (int i = 0; i < 16; ++i) {
      while (((q[i] ^ tagpat) & 0x0000FFFF0000FFFFull) != 0ull)
        q[i] = cload64(src + i * 256 + tid);
      uint32_t lo = (uint32_t)q[i], hi = (uint32_t)(q[i] >> 32);
      *(uint32_t*)&ldsX[i][2 * tid] = (lo >> 16) | (hi & 0xFFFF0000u);
    }
  };

  float zv0 = 0.f, zv1 = 0.f, zv2 = 0.f, zv3 = 0.f;

  for (int t = 0; t < S_; ++t) {
    if (t > 0) {
      stage16(hTg, tbase | (uint32_t)t);   // h(t-1), written with tag t
      __syncthreads();
    }

    // ---------- phase A: z (waves 0,1) and r -> hr (waves 2,3) ----------
    v4f acc0 = {0,0,0,0}, acc1 = {0,0,0,0};
#pragma unroll
    for (int kk = 0; kk < 8; ++kk) {
      v8s a0 = *(const v8s*)&ldsX[fr][kk * 32 + kb];
      v8s b0 = *(const v8s*)(wA + kk * 32 + kb);
      acc0 = mfma16(a0, b0, acc0);
      v8s a1 = *(const v8s*)&ldsX[fr][256 + kk * 32 + kb];
      v8s b1 = *(const v8s*)(wA + 256 + kk * 32 + kb);
      acc1 = mfma16(a1, b1, acc1);
    }
    float pre[4];
#pragma unroll
    for (int j = 0; j < 4; ++j) {
      int b = gb + rb + j;
      float x = bf2f(xA[((size_t)b * S_ + t) * H_ + gcol]);
      float s = acc0[j] + acc1[j] + x + biasA;
      pre[j] = 1.0f / (1.0f + __expf(-s));
    }
    const uint32_t tagw = tbase | (uint32_t)(t + 1);
    if (gateA == 0) {
      zv0 = pre[0]; zv1 = pre[1]; zv2 = pre[2]; zv3 = pre[3];
    } else {
#pragma unroll
      for (int j = 0; j < 4; ++j) {
        float v = pre[j] * h32[rb + j][colL];
        cstore32(&hrTg[(size_t)(rb + j) * 512 + gcol],
                 ((uint32_t)f2bf(v) << 16) | tagw);
      }
    }
    __syncthreads();                      // ldsX(h) reads done before overwrite

    stage16(hrTg, tagw);                  // hr(t)
    __syncthreads();

    // ---------- phase B: g (waves 0,1), h update ----------
    if (w < 2) {
      v4f g0 = {0,0,0,0}, g1 = {0,0,0,0};
#pragma unroll
      for (int kk = 0; kk < 8; ++kk) {
        v8s a0 = *(const v8s*)&ldsX[fr][kk * 32 + kb];
        v8s b0 = *(const v8s*)(wG + kk * 32 + kb);
        g0 = mfma16(a0, b0, g0);
        v8s a1 = *(const v8s*)&ldsX[fr][256 + kk * 32 + kb];
        v8s b1 = *(const v8s*)(wG + 256 + kk * 32 + kb);
        g1 = mfma16(a1, b1, g1);
      }
      float zv[4] = {zv0, zv1, zv2, zv3};
#pragma unroll
      for (int j = 0; j < 4; ++j) {
        int b = gb + rb + j;
        float xg = bf2f(xG[((size_t)b * S_ + t) * H_ + gcol]);
        float gval = tanhf(g0[j] + g1[j] + xg + biasG);
        float hold = h32[rb + j][colL];
        float hnew = zv[j] * hold + (1.0f - zv[j]) * gval;
        h32[rb + j][colL] = hnew;
        uint32_t c0 = f2bf(hnew);
        cstore32(&hTg[(size_t)(rb + j) * 512 + gcol], (c0 << 16) | tagw);
        // seqout: pack 4 bf16 cols into one u64 store
        float o1 = __shfl_xor(hnew, 1);
        uint32_t c1 = f2bf(o1);
        uint32_t pk = (fr & 1) ? (c1 | (c0 << 16)) : (c0 | (c1 << 16));
        uint32_t pk2 = __shfl_xor(pk, 2);
        if ((fr & 3) == 0) {
          uint64_t qv = (uint64_t)pk | ((uint64_t)pk2 << 32);
          *(uint64_t*)&seqout[((size_t)b * S_ + t) * H_ + gcol] = qv;
        }
        if (t == S_ - 1) hfinal[(size_t)b * H_ + gcol] = hnew;
      }
    }
    __syncthreads();                      // ldsX(hr) reads done before next stage
  }
}

// ---------------------------------------------------------------- launch
extern "C" void kernel_launch(void* const* d_in, const int* in_sizes, int n_in,
                              void* d_out, int out_size, void* d_ws,
                              size_t ws_size, hipStream_t stream) {
  const float* input = (const float*)d_in[0];
  const float* hs = (const float*)d_in[1];
  const float* W_in[2][3] = {
      {(const float*)d_in[2], (const float*)d_in[5], (const float*)d_in[8]},
      {(const float*)d_in[11], (const float*)d_in[14], (const float*)d_in[17]}};
  const float* W_h[2][3] = {
      {(const float*)d_in[3], (const float*)d_in[6], (const float*)d_in[9]},
      {(const float*)d_in[12], (const float*)d_in[15], (const float*)d_in[18]}};
  const float* bias[2][3] = {
      {(const float*)d_in[4], (const float*)d_in[7], (const float*)d_in[10]},
      {(const float*)d_in[13], (const float*)d_in[16], (const float*)d_in[19]}};
  const float* Wo = (const float*)d_in[20];
  const float* bo = (const float*)d_in[21];
  float* out = (float*)d_out;

  // ---------------- workspace layout (peak ~207.5 MB) ----------------
  char* ws = (char*)d_ws;
  u16* xproj   = (u16*)(ws + 0);             // 201,326,592 B
  u16* wtin0   = (u16*)(ws + 201326592);     // [1536][256]
  u16* wth0    = (u16*)(ws + 202113024);     // [3][512][512]
  u16* wtin1   = (u16*)(ws + 203685888);     // [1536][512]
  u16* wth1    = (u16*)(ws + 205258752);     // [3][512][512]
  u16* wot     = (u16*)(ws + 206831616);     // [256][512]
  uint32_t* hT  = (uint32_t*)(ws + 207093760); // [4][16][512] u32 = 131,072 B
  uint32_t* hrT = (uint32_t*)(ws + 207224832); // [4][16][512] u32 = 131,072 B

  u16* inbf  = (u16*)d_out;                  // 33.5 MB in d_out y-region
  u16* h1seq = (u16*)d_out;                  // 67.1 MB in d_out y-region
  u16* seq2  = xproj;                        // aliases z-gate slice

  // 0. clear exchange tags (stale tags from a previous replay)
  hipMemsetAsync(hT, 0, 262144, stream);

  // 1. cast input to bf16 (into d_out y-region scratch)
  cast_input_kernel<<<2048, 256, 0, stream>>>(input, inbf, BS_ * IN_ / 4);

  // 2. pack all weights (transpose + cast)
  for (int l = 0; l < 2; ++l) {
    int K = (l == 0) ? IN_ : H_;
    u16* win = (l == 0) ? wtin0 : wtin1;
    u16* wh = (l == 0) ? wth0 : wth1;
    for (int g = 0; g < 3; ++g) {
      pack_transpose_kernel<<<256, 256, 0, stream>>>(W_in[l][g],
                                                     win + (size_t)g * H_ * K, K, H_);
      pack_transpose_kernel<<<256, 256, 0, stream>>>(W_h[l][g],
                                                     wh + (size_t)g * H_ * H_, H_, H_);
    }
  }
  pack_transpose_kernel<<<256, 256, 0, stream>>>(Wo, wot, H_, OUT_);

  const size_t ysz = (size_t)BS_ * OUT_;

  for (int l = 0; l < 2; ++l) {
    const u16* Ain = (l == 0) ? inbf : h1seq;
    int K = (l == 0) ? IN_ : H_;
    gemm_kernel<<<dim3(24, 1024), 256, 0, stream>>>(
        Ain, (l == 0) ? wtin0 : wtin1, 1536, K, xproj, nullptr, nullptr, 0);

    u16* seqo = (l == 0) ? h1seq : seq2;
    float* hfin = out + ysz + (size_t)l * B_ * H_;
    const u16* wh = (l == 0) ? wth0 : wth1;
    gru_scan_kernel<<<dim3(NGRP_ * NSLAB_), dim3(256), 0, stream>>>(
        xproj, wh, bias[l][0], bias[l][1], bias[l][2], hs, l, hT, hrT,
        seqo, hfin);
  }

  // 3. output projection: y = seq2 @ Wo + bo (overwrites h1seq, dead by now)
  gemm_kernel<<<dim3(4, 1024), 256, 0, stream>>>(seq2, wot, OUT_, H_, nullptr,
                                                 out, bo, 1);
}

// Round 6
// 14744.084 us; speedup vs baseline: 1.7927x; 1.7927x over previous
//
#include <hip/hip_runtime.h>
#include <stdint.h>

typedef unsigned short u16;
typedef short v8s __attribute__((ext_vector_type(8)));
typedef float v4f __attribute__((ext_vector_type(4)));

#define B_ 64
#define S_ 1024
#define IN_ 256
#define H_ 512
#define OUT_ 256
#define BS_ (B_ * S_)                 // 65536
#define GS_ ((size_t)BS_ * H_)        // elems per gate buffer
#define NSLAB_ 16
#define NGRP_ 4
#define HP_ (H_ + 8)                  // padded LDS row (u16 elems)
#define FPAD_ 16                      // flag padding: 16 u32 = 64 B/line

static __device__ __forceinline__ u16 f2bf(float f) {
  uint32_t u = __float_as_uint(f);
  u += 0x7FFFu + ((u >> 16) & 1u);   // round-to-nearest-even
  return (u16)(u >> 16);
}
static __device__ __forceinline__ float bf2f(u16 h) {
  return __uint_as_float(((uint32_t)h) << 16);
}
static __device__ __forceinline__ v4f mfma16(v8s a, v8s b, v4f c) {
  return __builtin_amdgcn_mfma_f32_16x16x32_bf16(a, b, c, 0, 0, 0);
}
// Coherent (agent-scope, relaxed) accesses: served at the coherence point;
// no fences, no L2 invalidate/writeback.  (r3-proven protocol.)
static __device__ __forceinline__ uint64_t cload64(const uint64_t* p) {
  return __hip_atomic_load(p, __ATOMIC_RELAXED, __HIP_MEMORY_SCOPE_AGENT);
}
static __device__ __forceinline__ void cstore64(uint64_t* p, uint64_t v) {
  __hip_atomic_store(p, v, __ATOMIC_RELAXED, __HIP_MEMORY_SCOPE_AGENT);
}

// De-contended group barrier: per-slab flag words padded to one 64 B line
// each (no RMW, no shared hot word). Caller must have executed
// s_waitcnt vmcnt(0) on every wave with outstanding exchange stores.
static __device__ __forceinline__ void slab_barrier(uint32_t* flagbase,
                                                    int slab, uint32_t want,
                                                    int tid) {
  __syncthreads();                    // all waves' stores issued+acked
  if (tid == 0)
    __hip_atomic_store(flagbase + slab * FPAD_, want, __ATOMIC_RELAXED,
                       __HIP_MEMORY_SCOPE_AGENT);
  if (tid < NSLAB_) {
    while (__hip_atomic_load(flagbase + tid * FPAD_, __ATOMIC_RELAXED,
                             __HIP_MEMORY_SCOPE_AGENT) < want)
      __builtin_amdgcn_s_sleep(1);
  }
  __syncthreads();
}

// ---------------------------------------------------------------- utilities
__global__ void cast_input_kernel(const float* __restrict__ src,
                                  u16* __restrict__ dst, int n4) {
  int i = blockIdx.x * blockDim.x + threadIdx.x;
  int stride = gridDim.x * blockDim.x;
  for (; i < n4; i += stride) {
    float4 v = ((const float4*)src)[i];
    uint32_t lo = (uint32_t)f2bf(v.x) | ((uint32_t)f2bf(v.y) << 16);
    uint32_t hi = (uint32_t)f2bf(v.z) | ((uint32_t)f2bf(v.w) << 16);
    ((uint2*)dst)[i] = make_uint2(lo, hi);
  }
}

// dst[n*K + k] = bf16(src[k*N + n])   (transpose + cast)
__global__ void pack_transpose_kernel(const float* __restrict__ src,
                                      u16* __restrict__ dst, int K, int N) {
  int i = blockIdx.x * blockDim.x + threadIdx.x;
  int total = K * N;
  int stride = gridDim.x * blockDim.x;
  for (; i < total; i += stride) {
    int n = i / K, k = i - n * K;
    dst[i] = f2bf(src[(size_t)k * N + n]);
  }
}

// ---------------------------------------------------------------- GEMM
// C[M x N] = A[M x K] * Bt[N x K]^T ; 64x64 block tile, 4 waves of 32x32.
// mode 0: bf16 out split into 3 gate buffers of [BS_][H_] (N = 1536)
// mode 1: f32 out with bias (N = OUT_)
__global__ void __launch_bounds__(256) gemm_kernel(
    const u16* __restrict__ A, const u16* __restrict__ Bt, int N, int K,
    u16* __restrict__ outb, float* __restrict__ outf,
    const float* __restrict__ bias, int mode) {
  const int bn = blockIdx.x * 64;
  const int bm = blockIdx.y * 64;
  const int w = threadIdx.x >> 6;
  const int lane = threadIdx.x & 63;
  const int wm = (w >> 1) * 32, wn = (w & 1) * 32;
  const int fr = lane & 15;
  const int kb = (lane >> 4) * 8;
  v4f acc00 = {0,0,0,0}, acc01 = {0,0,0,0}, acc10 = {0,0,0,0}, acc11 = {0,0,0,0};
  const u16* a0p = A + (size_t)(bm + wm + fr) * K + kb;
  const u16* a1p = a0p + (size_t)16 * K;
  const u16* b0p = Bt + (size_t)(bn + wn + fr) * K + kb;
  const u16* b1p = b0p + (size_t)16 * K;
  for (int kk = 0; kk < K; kk += 32) {
    v8s a0 = *(const v8s*)(a0p + kk);
    v8s a1 = *(const v8s*)(a1p + kk);
    v8s b0 = *(const v8s*)(b0p + kk);
    v8s b1 = *(const v8s*)(b1p + kk);
    acc00 = mfma16(a0, b0, acc00);
    acc01 = mfma16(a0, b1, acc01);
    acc10 = mfma16(a1, b0, acc10);
    acc11 = mfma16(a1, b1, acc11);
  }
  v4f accs[2][2] = {{acc00, acc01}, {acc10, acc11}};
  const int rb = (lane >> 4) * 4;
#pragma unroll
  for (int mi = 0; mi < 2; ++mi)
#pragma unroll
    for (int ni = 0; ni < 2; ++ni)
#pragma unroll
      for (int j = 0; j < 4; ++j) {
        int row = bm + wm + mi * 16 + rb + j;
        int col = bn + wn + ni * 16 + fr;
        float v = accs[mi][ni][j];
        if (mode == 0) {
          int gate = col >> 9, c = col & (H_ - 1);
          outb[(size_t)gate * GS_ + (size_t)row * H_ + c] = f2bf(v);
        } else {
          outf[(size_t)row * N + col] = v + bias[col];
        }
      }
}

// ---------------------------------------------------------------- GRU scan
// 64 WGs = 4 batch-groups (16 rows) x 16 column-slabs (32 cols).
// Recurrent weight slabs live in LDS for all 1024 steps. h / hr are
// exchanged through relaxed agent-scope atomics (coherence point), with
// per-slab PADDED flag words (pure stores + parallel 16-line poll — no
// RMW contention). Release order: data stores -> vmcnt(0) -> syncthreads
// -> flag store.  (r3-proven dataflow; only the barrier is de-contended.)
// NOTE: xproj and seqout may alias for layer 1 -> no __restrict__ on them.
__global__ void __launch_bounds__(256, 1) gru_scan_kernel(
    const u16* xproj,                // [3][BS_][H_] bf16 (z,r,g)
    const u16* __restrict__ Wht,     // [3][H_][H_] bf16, Wt[g][n][k] = W[k][n]
    const float* __restrict__ bz, const float* __restrict__ br,
    const float* __restrict__ bg,
    const float* __restrict__ hs,    // [B_][2][H_] f32 initial state
    int layer,
    u16* hbuf,                       // [NGRP_*16][512] bf16 exchange
    u16* hrbuf,                      // [NGRP_*16][512] bf16 exchange
    u16* seqout,                     // [B_][S_][H_] bf16
    float* __restrict__ hfinal,      // [B_][H_] f32 (d_out tail slice)
    uint32_t* flags) {               // [2][NGRP_][NSLAB_][FPAD_] u32, zeroed
  __shared__ __align__(16) u16 ldsW[3][32][HP_];  // 99,840 B
  __shared__ __align__(16) u16 ldsX[16][HP_];     // 16,640 B (h / hr staging)
  __shared__ float h32[16][32];                   //  2,048 B (own-col f32 h)
  const int grp = blockIdx.x & (NGRP_ - 1);
  const int slab = blockIdx.x >> 2;
  const int j0 = slab * 32;
  const int tid = threadIdx.x;
  const int gb = grp * 16;          // batch row base of this group

  // stage weight slabs (once)
  for (int idx = tid; idx < 3 * 32 * 64; idx += 256) {
    int gate = idx >> 11;
    int rem = idx & 2047;
    int cl = rem >> 6;
    int kc = (rem & 63) * 8;
    *(v8s*)&ldsW[gate][cl][kc] =
        *(const v8s*)(Wht + ((size_t)gate * H_ + (j0 + cl)) * H_ + kc);
  }
  // h0 init: bf16 full block + f32 own columns
  for (int i = tid; i < 16 * H_; i += 256) {
    int row = i >> 9, col = i & (H_ - 1);
    ldsX[row][col] = f2bf(hs[((size_t)(gb + row) * 2 + layer) * H_ + col]);
  }
  for (int i = tid; i < 16 * 32; i += 256) {
    int row = i >> 5, cl = i & 31;
    h32[row][cl] = hs[((size_t)(gb + row) * 2 + layer) * H_ + j0 + cl];
  }
  __syncthreads();

  const int w = tid >> 6, lane = tid & 63;
  const int fr = lane & 15;
  const int kb = (lane >> 4) * 8;
  const int rb = (lane >> 4) * 4;
  const int nt = w & 1;             // N-tile within slab
  const int gateA = w >> 1;         // waves 0,1 -> z ; waves 2,3 -> r
  const int colL = nt * 16 + fr;
  const int gcol = j0 + colL;
  const float biasA = (gateA == 0) ? bz[gcol] : br[gcol];
  const float biasG = bg[gcol];

  u16* hbuf_g = hbuf + (size_t)gb * H_;
  u16* hrbuf_g = hrbuf + (size_t)gb * H_;
  const u16* xA = xproj + (size_t)gateA * GS_;
  const u16* xG = xproj + (size_t)2 * GS_;
  const u16* wA = &ldsW[gateA][colL][0];
  const u16* wG = &ldsW[2][colL][0];
  uint32_t* flagA = flags + (size_t)(0 * NGRP_ + grp) * NSLAB_ * FPAD_;
  uint32_t* flagB = flags + (size_t)(1 * NGRP_ + grp) * NSLAB_ * FPAD_;

  float zv0 = 0.f, zv1 = 0.f, zv2 = 0.f, zv3 = 0.f;

  for (int t = 0; t < S_; ++t) {
    if (t > 0) {
      // stage h(t-1) block: 2048 qwords, coherent
      uint64_t vq[8];
#pragma unroll
      for (int i = 0; i < 8; ++i)
        vq[i] = cload64((const uint64_t*)hbuf_g + i * 256 + tid);
#pragma unroll
      for (int i = 0; i < 8; ++i) {
        int d = i * 256 + tid;
        *(uint64_t*)&ldsX[d >> 7][(d & 127) * 4] = vq[i];
      }
      __syncthreads();
    }

    // ---------- phase A: z (waves 0,1) and r -> hr (waves 2,3) ----------
    // hoist x-projection loads ahead of the MFMA chain (independent)
    float xpre[4];
#pragma unroll
    for (int j = 0; j < 4; ++j)
      xpre[j] = bf2f(xA[((size_t)(gb + rb + j) * S_ + t) * H_ + gcol]);
    v4f acc0 = {0,0,0,0}, acc1 = {0,0,0,0};
#pragma unroll
    for (int kk = 0; kk < 8; ++kk) {
      v8s a0 = *(const v8s*)&ldsX[fr][kk * 32 + kb];
      v8s b0 = *(const v8s*)(wA + kk * 32 + kb);
      acc0 = mfma16(a0, b0, acc0);
      v8s a1 = *(const v8s*)&ldsX[fr][256 + kk * 32 + kb];
      v8s b1 = *(const v8s*)(wA + 256 + kk * 32 + kb);
      acc1 = mfma16(a1, b1, acc1);
    }
    float pre[4];
#pragma unroll
    for (int j = 0; j < 4; ++j) {
      float s = acc0[j] + acc1[j] + xpre[j] + biasA;
      pre[j] = 1.0f / (1.0f + __expf(-s));
    }
    if (gateA == 0) {
      zv0 = pre[0]; zv1 = pre[1]; zv2 = pre[2]; zv3 = pre[3];
    } else {
#pragma unroll
      for (int j = 0; j < 4; ++j) {
        float v = pre[j] * h32[rb + j][colL];
        float o1 = __shfl_xor(v, 1);
        uint32_t c0 = f2bf(v), c1 = f2bf(o1);
        uint32_t pk = (fr & 1) ? (c1 | (c0 << 16)) : (c0 | (c1 << 16));
        uint32_t pk2 = __shfl_xor(pk, 2);
        if ((fr & 3) == 0) {
          uint64_t q = (uint64_t)pk | ((uint64_t)pk2 << 32);
          cstore64((uint64_t*)&hrbuf_g[(size_t)(rb + j) * H_ + gcol], q);
        }
      }
    }
    asm volatile("s_waitcnt vmcnt(0)" ::: "memory");  // ack exchange stores
    slab_barrier(flagA, slab, (uint32_t)(t + 1), tid);

    // stage hr block
    {
      uint64_t vq[8];
#pragma unroll
      for (int i = 0; i < 8; ++i)
        vq[i] = cload64((const uint64_t*)hrbuf_g + i * 256 + tid);
#pragma unroll
      for (int i = 0; i < 8; ++i) {
        int d = i * 256 + tid;
        *(uint64_t*)&ldsX[d >> 7][(d & 127) * 4] = vq[i];
      }
      __syncthreads();
    }

    // ---------- phase B: g (waves 0,1), h update ----------
    if (w < 2) {
      float xpg[4];
#pragma unroll
      for (int j = 0; j < 4; ++j)
        xpg[j] = bf2f(xG[((size_t)(gb + rb + j) * S_ + t) * H_ + gcol]);
      v4f g0 = {0,0,0,0}, g1 = {0,0,0,0};
#pragma unroll
      for (int kk = 0; kk < 8; ++kk) {
        v8s a0 = *(const v8s*)&ldsX[fr][kk * 32 + kb];
        v8s b0 = *(const v8s*)(wG + kk * 32 + kb);
        g0 = mfma16(a0, b0, g0);
        v8s a1 = *(const v8s*)&ldsX[fr][256 + kk * 32 + kb];
        v8s b1 = *(const v8s*)(wG + 256 + kk * 32 + kb);
        g1 = mfma16(a1, b1, g1);
      }
      float zv[4] = {zv0, zv1, zv2, zv3};
#pragma unroll
      for (int j = 0; j < 4; ++j) {
        int b = gb + rb + j;
        float gval = tanhf(g0[j] + g1[j] + xpg[j] + biasG);
        float hold = h32[rb + j][colL];
        float hnew = zv[j] * hold + (1.0f - zv[j]) * gval;
        h32[rb + j][colL] = hnew;
        uint32_t c0 = f2bf(hnew);
        float o1 = __shfl_xor(hnew, 1);
        uint32_t c1 = f2bf(o1);
        uint32_t pk = (fr & 1) ? (c1 | (c0 << 16)) : (c0 | (c1 << 16));
        uint32_t pk2 = __shfl_xor(pk, 2);
        if ((fr & 3) == 0) {
          uint64_t qv = (uint64_t)pk | ((uint64_t)pk2 << 32);
          cstore64((uint64_t*)&hbuf_g[(size_t)(rb + j) * H_ + gcol], qv);
          *(uint64_t*)&seqout[((size_t)b * S_ + t) * H_ + gcol] = qv;
        }
        if (t == S_ - 1) hfinal[(size_t)b * H_ + gcol] = hnew;
      }
    }
    asm volatile("s_waitcnt vmcnt(0)" ::: "memory");  // ack exchange stores
    slab_barrier(flagB, slab, (uint32_t)(t + 1), tid);
  }
}

// ---------------------------------------------------------------- launch
extern "C" void kernel_launch(void* const* d_in, const int* in_sizes, int n_in,
                              void* d_out, int out_size, void* d_ws,
                              size_t ws_size, hipStream_t stream) {
  const float* input = (const float*)d_in[0];
  const float* hs = (const float*)d_in[1];
  const float* W_in[2][3] = {
      {(const float*)d_in[2], (const float*)d_in[5], (const float*)d_in[8]},
      {(const float*)d_in[11], (const float*)d_in[14], (const float*)d_in[17]}};
  const float* W_h[2][3] = {
      {(const float*)d_in[3], (const float*)d_in[6], (const float*)d_in[9]},
      {(const float*)d_in[12], (const float*)d_in[15], (const float*)d_in[18]}};
  const float* bias[2][3] = {
      {(const float*)d_in[4], (const float*)d_in[7], (const float*)d_in[10]},
      {(const float*)d_in[13], (const float*)d_in[16], (const float*)d_in[19]}};
  const float* Wo = (const float*)d_in[20];
  const float* bo = (const float*)d_in[21];
  float* out = (float*)d_out;

  // ---------------- workspace layout (peak ~207.5 MB) ----------------
  char* ws = (char*)d_ws;
  u16* xproj   = (u16*)(ws + 0);             // 201,326,592 B
  u16* wtin0   = (u16*)(ws + 201326592);     // [1536][256]
  u16* wth0    = (u16*)(ws + 202113024);     // [3][512][512]
  u16* wtin1   = (u16*)(ws + 203685888);     // [1536][512]
  u16* wth1    = (u16*)(ws + 205258752);     // [3][512][512]
  u16* wot     = (u16*)(ws + 206831616);     // [256][512]
  u16* hbuf    = (u16*)(ws + 207093760);     // [64][512] bf16 exchange
  u16* hrbuf   = (u16*)(ws + 207159296);     // [64][512] bf16 exchange
  uint32_t* flags = (uint32_t*)(ws + 207224832); // 2*4*16*16 u32 = 8,192 B

  u16* inbf  = (u16*)d_out;                  // 33.5 MB in d_out y-region
  u16* h1seq = (u16*)d_out;                  // 67.1 MB in d_out y-region
  u16* seq2  = xproj;                        // aliases z-gate slice

  // 1. cast input to bf16 (into d_out y-region scratch)
  cast_input_kernel<<<2048, 256, 0, stream>>>(input, inbf, BS_ * IN_ / 4);

  // 2. pack all weights (transpose + cast)
  for (int l = 0; l < 2; ++l) {
    int K = (l == 0) ? IN_ : H_;
    u16* win = (l == 0) ? wtin0 : wtin1;
    u16* wh = (l == 0) ? wth0 : wth1;
    for (int g = 0; g < 3; ++g) {
      pack_transpose_kernel<<<256, 256, 0, stream>>>(W_in[l][g],
                                                     win + (size_t)g * H_ * K, K, H_);
      pack_transpose_kernel<<<256, 256, 0, stream>>>(W_h[l][g],
                                                     wh + (size_t)g * H_ * H_, H_, H_);
    }
  }
  pack_transpose_kernel<<<256, 256, 0, stream>>>(Wo, wot, H_, OUT_);

  const size_t ysz = (size_t)BS_ * OUT_;

  for (int l = 0; l < 2; ++l) {
    const u16* Ain = (l == 0) ? inbf : h1seq;
    int K = (l == 0) ? IN_ : H_;
    gemm_kernel<<<dim3(24, 1024), 256, 0, stream>>>(
        Ain, (l == 0) ? wtin0 : wtin1, 1536, K, xproj, nullptr, nullptr, 0);

    // zero the padded per-slab flags before each scan
    hipMemsetAsync(flags, 0, 8192, stream);

    u16* seqo = (l == 0) ? h1seq : seq2;
    float* hfin = out + ysz + (size_t)l * B_ * H_;
    const u16* wh = (l == 0) ? wth0 : wth1;
    gru_scan_kernel<<<dim3(NGRP_ * NSLAB_), dim3(256), 0, stream>>>(
        xproj, wh, bias[l][0], bias[l][1], bias[l][2], hs, l, hbuf, hrbuf,
        seqo, hfin, flags);
  }

  // 3. output projection: y = seq2 @ Wo + bo (overwrites h1seq, dead by now)
  gemm_kernel<<<dim3(4, 1024), 256, 0, stream>>>(seq2, wot, OUT_, H_, nullptr,
                                                 out, bo, 1);
}

// Round 7
// 7385.740 us; speedup vs baseline: 3.5787x; 1.9963x over previous
//
#include <hip/hip_runtime.h>
#include <stdint.h>

typedef unsigned short u16;
typedef short v8s __attribute__((ext_vector_type(8)));
typedef float v4f __attribute__((ext_vector_type(4)));

#define B_ 64
#define S_ 1024
#define IN_ 256
#define H_ 512
#define OUT_ 256
#define BS_ (B_ * S_)                 // 65536
#define GS_ ((size_t)BS_ * H_)        // elems per gate buffer
#define HP_ (H_ + 8)                  // padded LDS row, L0 (u16)
#define KP1_ (1024 + 8)               // padded LDS row, L1 stacked-K (u16)
#define FPAD_ 16                      // flag padding: 16 u32 = 64 B/line

static __device__ __forceinline__ u16 f2bf(float f) {
  uint32_t u = __float_as_uint(f);
  u += 0x7FFFu + ((u >> 16) & 1u);   // round-to-nearest-even
  return (u16)(u >> 16);
}
static __device__ __forceinline__ float bf2f(u16 h) {
  return __uint_as_float(((uint32_t)h) << 16);
}
static __device__ __forceinline__ v4f mfma16(v8s a, v8s b, v4f c) {
  return __builtin_amdgcn_mfma_f32_16x16x32_bf16(a, b, c, 0, 0, 0);
}
// Relaxed agent-scope accesses: served at the coherence point (r3/r6-proven).
static __device__ __forceinline__ uint64_t cload64(const uint64_t* p) {
  return __hip_atomic_load(p, __ATOMIC_RELAXED, __HIP_MEMORY_SCOPE_AGENT);
}
static __device__ __forceinline__ void cstore64(uint64_t* p, uint64_t v) {
  __hip_atomic_store(p, v, __ATOMIC_RELAXED, __HIP_MEMORY_SCOPE_AGENT);
}
static __device__ __forceinline__ void cstore32(uint32_t* p, uint32_t v) {
  __hip_atomic_store(p, v, __ATOMIC_RELAXED, __HIP_MEMORY_SCOPE_AGENT);
}
static __device__ __forceinline__ void pollge(const uint32_t* p, uint32_t want) {
  while (__hip_atomic_load(p, __ATOMIC_RELAXED, __HIP_MEMORY_SCOPE_AGENT) < want)
    __builtin_amdgcn_s_sleep(1);
}
// De-contended group barrier over NS padded flag lines (r6-proven).
// Caller must have drained exchange stores (vmcnt(0)) on every wave.
template <int NS>
static __device__ __forceinline__ void slab_barrier(uint32_t* flagbase,
                                                    int slab, uint32_t want,
                                                    int tid) {
  __syncthreads();
  if (tid == 0)
    __hip_atomic_store(flagbase + slab * FPAD_, want, __ATOMIC_RELAXED,
                       __HIP_MEMORY_SCOPE_AGENT);
  if (tid < NS) pollge(flagbase + tid * FPAD_, want);
  __syncthreads();
}

// ---------------------------------------------------------------- utilities
__global__ void cast_input_kernel(const float* __restrict__ src,
                                  u16* __restrict__ dst, int n4) {
  int i = blockIdx.x * blockDim.x + threadIdx.x;
  int stride = gridDim.x * blockDim.x;
  for (; i < n4; i += stride) {
    float4 v = ((const float4*)src)[i];
    uint32_t lo = (uint32_t)f2bf(v.x) | ((uint32_t)f2bf(v.y) << 16);
    uint32_t hi = (uint32_t)f2bf(v.z) | ((uint32_t)f2bf(v.w) << 16);
    ((uint2*)dst)[i] = make_uint2(lo, hi);
  }
}

// dst[n*dstK + k0 + k] = bf16(src[k*N + n])  (transpose+cast, strided dst for
// stacked-K packing)
__global__ void pack_transpose_k(const float* __restrict__ src,
                                 u16* __restrict__ dst, int K, int N,
                                 int dstK, int k0) {
  int i = blockIdx.x * blockDim.x + threadIdx.x;
  int total = K * N;
  int stride = gridDim.x * blockDim.x;
  for (; i < total; i += stride) {
    int n = i / K, k = i - n * K;
    dst[(size_t)n * dstK + k0 + k] = f2bf(src[(size_t)k * N + n]);
  }
}

// ---------------------------------------------------------------- GEMM
// C[M x N] = A[M x K] * Bt[N x K]^T ; 64x64 block tile, 4 waves of 32x32.
__global__ void __launch_bounds__(256) gemm_kernel(
    const u16* __restrict__ A, const u16* __restrict__ Bt, int N, int K,
    u16* __restrict__ outb, float* __restrict__ outf,
    const float* __restrict__ bias, int mode) {
  const int bn = blockIdx.x * 64;
  const int bm = blockIdx.y * 64;
  const int w = threadIdx.x >> 6;
  const int lane = threadIdx.x & 63;
  const int wm = (w >> 1) * 32, wn = (w & 1) * 32;
  const int fr = lane & 15;
  const int kb = (lane >> 4) * 8;
  v4f acc00 = {0,0,0,0}, acc01 = {0,0,0,0}, acc10 = {0,0,0,0}, acc11 = {0,0,0,0};
  const u16* a0p = A + (size_t)(bm + wm + fr) * K + kb;
  const u16* a1p = a0p + (size_t)16 * K;
  const u16* b0p = Bt + (size_t)(bn + wn + fr) * K + kb;
  const u16* b1p = b0p + (size_t)16 * K;
  for (int kk = 0; kk < K; kk += 32) {
    v8s a0 = *(const v8s*)(a0p + kk);
    v8s a1 = *(const v8s*)(a1p + kk);
    v8s b0 = *(const v8s*)(b0p + kk);
    v8s b1 = *(const v8s*)(b1p + kk);
    acc00 = mfma16(a0, b0, acc00);
    acc01 = mfma16(a0, b1, acc01);
    acc10 = mfma16(a1, b0, acc10);
    acc11 = mfma16(a1, b1, acc11);
  }
  v4f accs[2][2] = {{acc00, acc01}, {acc10, acc11}};
  const int rb = (lane >> 4) * 4;
#pragma unroll
  for (int mi = 0; mi < 2; ++mi)
#pragma unroll
    for (int ni = 0; ni < 2; ++ni)
#pragma unroll
      for (int j = 0; j < 4; ++j) {
        int row = bm + wm + mi * 16 + rb + j;
        int col = bn + wn + ni * 16 + fr;
        float v = accs[mi][ni][j];
        if (mode == 0) {
          int gate = col >> 9, c = col & (H_ - 1);
          outb[(size_t)gate * GS_ + (size_t)row * H_ + c] = f2bf(v);
        } else {
          outf[(size_t)row * N + col] = v + bias[col];
        }
      }
}

// ---------------------------------------------------------------- pipelined
// two-layer GRU scan. 192 WGs:
//   bid <  64 : layer-0 role — 4 grp x 16 slabs x 32 cols (r6 protocol;
//               parity-double-buffered h broadcast + L1 backpressure poll).
//   bid >= 64 : layer-1 role — 4 grp x 32 slabs x 16 cols; consumes L0's
//               h(t) broadcast; stacked-K [h0(t); h1(t-1)] @ [Win; Wh]
//               (K=1024) folds the input projection into the gate matmul.
// xproj/seqout alias (L1 writes seq over L0's consumed z-slice): no restrict.
__global__ void __launch_bounds__(256, 1) gru_pipe_kernel(
    const u16* xproj,                // [3][BS_][H_] bf16 (layer-0 z,r,g)
    const u16* __restrict__ Wht0,    // [3][H_][H_]  layer-0 recurrent^T
    const u16* __restrict__ Wstk1,   // [3][H_][1024] layer-1 stacked [Win;Wh]^T
    const float* __restrict__ bz0, const float* __restrict__ br0,
    const float* __restrict__ bg0,
    const float* __restrict__ bz1, const float* __restrict__ br1,
    const float* __restrict__ bg1,
    const float* __restrict__ hs,    // [B_][2][H_] f32 initial state
    u16* h0buf,                      // [2][B_][H_] L0 h broadcast (parity)
    u16* hr0buf,                     // [B_][H_]    L0 hr exchange
    u16* h1buf,                      // [B_][H_]    L1 h broadcast
    u16* hr1buf,                     // [B_][H_]    L1 hr exchange
    u16* seqout,                     // [B_][S_][H_] layer-1 output (alias z)
    float* __restrict__ hfinal,      // [2*B_][H_] f32 (d_out tail)
    uint32_t* flags) {
  __shared__ __align__(16) char pool[134144];
  const int tid = threadIdx.x;
  const int bid = blockIdx.x;
  const int w = tid >> 6, lane = tid & 63;
  const int fr = lane & 15;
  const int kb = (lane >> 4) * 8;
  const int rb = (lane >> 4) * 4;

  if (bid < 64) {
    // ================= LAYER 0 =================
    u16* ldsW = (u16*)pool;                            // [3][32][HP_]
    u16 (*ldsX)[HP_] = (u16(*)[HP_])(pool + 99840);    // [16][HP_]
    float (*h32)[32] = (float(*)[32])(pool + 116480);  // [16][32]
    const int grp = bid & 3;
    const int slab = bid >> 2;
    const int j0 = slab * 32;
    const int gb = grp * 16;

    for (int idx = tid; idx < 3 * 32 * 64; idx += 256) {
      int gate = idx >> 11;
      int rem = idx & 2047;
      int cl = rem >> 6;
      int kc = (rem & 63) * 8;
      *(v8s*)&ldsW[((gate * 32) + cl) * HP_ + kc] =
          *(const v8s*)(Wht0 + ((size_t)gate * H_ + (j0 + cl)) * H_ + kc);
    }
    for (int i = tid; i < 16 * H_; i += 256) {
      int row = i >> 9, col = i & (H_ - 1);
      ldsX[row][col] = f2bf(hs[((size_t)(gb + row) * 2 + 0) * H_ + col]);
    }
    for (int i = tid; i < 16 * 32; i += 256) {
      int row = i >> 5, cl = i & 31;
      h32[row][cl] = hs[((size_t)(gb + row) * 2 + 0) * H_ + j0 + cl];
    }
    __syncthreads();

    const int nt = w & 1;
    const int gateA = w >> 1;          // waves 0,1 -> z ; waves 2,3 -> r
    const int colL = nt * 16 + fr;
    const int gcol = j0 + colL;
    const float biasA = (gateA == 0) ? bz0[gcol] : br0[gcol];
    const float biasG = bg0[gcol];
    u16* hr0_g = hr0buf + (size_t)gb * H_;
    const u16* xA = xproj + (size_t)gateA * GS_;
    const u16* xG = xproj + (size_t)2 * GS_;
    const u16* wA = ldsW + ((size_t)(gateA * 32) + colL) * HP_;
    const u16* wG = ldsW + ((size_t)(2 * 32) + colL) * HP_;
    uint32_t* flagA0 = flags + (size_t)grp * 16 * FPAD_;
    uint32_t* flagB0 = flags + 1024 + (size_t)grp * 16 * FPAD_;
    uint32_t* c1g    = flags + 6144 + (size_t)grp * 32 * FPAD_;

    float zv0 = 0.f, zv1 = 0.f, zv2 = 0.f, zv3 = 0.f;

    for (int t = 0; t < S_; ++t) {
      if (t > 0) {
        // backpressure: L1 must have staged h0(t-2) before we overwrite
        // parity buffer (t&1) in this step's phase B
        if (t >= 2 && tid < 32) pollge(c1g + tid * FPAD_, (uint32_t)(t - 1));
        const uint64_t* src =
            (const uint64_t*)(h0buf + ((size_t)((t - 1) & 1) * B_ + gb) * H_);
        uint64_t vq[8];
#pragma unroll
        for (int i = 0; i < 8; ++i) vq[i] = cload64(src + i * 256 + tid);
#pragma unroll
        for (int i = 0; i < 8; ++i) {
          int d = i * 256 + tid;
          *(uint64_t*)&ldsX[d >> 7][(d & 127) * 4] = vq[i];
        }
        __syncthreads();
      }

      // ---- phase A: z (waves 0,1), r -> hr (waves 2,3) ----
      float xpre[4];
#pragma unroll
      for (int j = 0; j < 4; ++j)
        xpre[j] = bf2f(xA[((size_t)(gb + rb + j) * S_ + t) * H_ + gcol]);
      v4f acc0 = {0,0,0,0}, acc1 = {0,0,0,0};
#pragma unroll
      for (int kk = 0; kk < 8; ++kk) {
        acc0 = mfma16(*(const v8s*)&ldsX[fr][kk * 32 + kb],
                      *(const v8s*)(wA + kk * 32 + kb), acc0);
        acc1 = mfma16(*(const v8s*)&ldsX[fr][256 + kk * 32 + kb],
                      *(const v8s*)(wA + 256 + kk * 32 + kb), acc1);
      }
      float pre[4];
#pragma unroll
      for (int j = 0; j < 4; ++j) {
        float s = acc0[j] + acc1[j] + xpre[j] + biasA;
        pre[j] = 1.0f / (1.0f + __expf(-s));
      }
      if (gateA == 0) {
        zv0 = pre[0]; zv1 = pre[1]; zv2 = pre[2]; zv3 = pre[3];
      } else {
#pragma unroll
        for (int j = 0; j < 4; ++j) {
          float v = pre[j] * h32[rb + j][colL];
          float o1 = __shfl_xor(v, 1);
          uint32_t c0 = f2bf(v), c1 = f2bf(o1);
          uint32_t pk = (fr & 1) ? (c1 | (c0 << 16)) : (c0 | (c1 << 16));
          uint32_t pk2 = __shfl_xor(pk, 2);
          if ((fr & 3) == 0)
            cstore64((uint64_t*)&hr0_g[(size_t)(rb + j) * H_ + gcol],
                     (uint64_t)pk | ((uint64_t)pk2 << 32));
        }
      }
      asm volatile("s_waitcnt vmcnt(0)" ::: "memory");
      slab_barrier<16>(flagA0, slab, (uint32_t)(t + 1), tid);

      {  // stage hr
        const uint64_t* src = (const uint64_t*)hr0_g;
        uint64_t vq[8];
#pragma unroll
        for (int i = 0; i < 8; ++i) vq[i] = cload64(src + i * 256 + tid);
#pragma unroll
        for (int i = 0; i < 8; ++i) {
          int d = i * 256 + tid;
          *(uint64_t*)&ldsX[d >> 7][(d & 127) * 4] = vq[i];
        }
        __syncthreads();
      }

      // ---- phase B: g (waves 0,1), h update + broadcast ----
      if (w < 2) {
        float xpg[4];
#pragma unroll
        for (int j = 0; j < 4; ++j)
          xpg[j] = bf2f(xG[((size_t)(gb + rb + j) * S_ + t) * H_ + gcol]);
        v4f g0 = {0,0,0,0}, g1 = {0,0,0,0};
#pragma unroll
        for (int kk = 0; kk < 8; ++kk) {
          g0 = mfma16(*(const v8s*)&ldsX[fr][kk * 32 + kb],
                      *(const v8s*)(wG + kk * 32 + kb), g0);
          g1 = mfma16(*(const v8s*)&ldsX[fr][256 + kk * 32 + kb],
                      *(const v8s*)(wG + 256 + kk * 32 + kb), g1);
        }
        float zv[4] = {zv0, zv1, zv2, zv3};
        u16* h0dst = h0buf + ((size_t)(t & 1) * B_ + gb) * H_;
#pragma unroll
        for (int j = 0; j < 4; ++j) {
          int b = gb + rb + j;
          float gval = tanhf(g0[j] + g1[j] + xpg[j] + biasG);
          float hold = h32[rb + j][colL];
          float hnew = zv[j] * hold + (1.0f - zv[j]) * gval;
          h32[rb + j][colL] = hnew;
          uint32_t c0 = f2bf(hnew);
          float o1 = __shfl_xor(hnew, 1);
          uint32_t c1 = f2bf(o1);
          uint32_t pk = (fr & 1) ? (c1 | (c0 << 16)) : (c0 | (c1 << 16));
          uint32_t pk2 = __shfl_xor(pk, 2);
          if ((fr & 3) == 0)
            cstore64((uint64_t*)&h0dst[(size_t)(rb + j) * H_ + gcol],
                     (uint64_t)pk | ((uint64_t)pk2 << 32));
          if (t == S_ - 1) hfinal[(size_t)b * H_ + gcol] = hnew;
        }
      }
      asm volatile("s_waitcnt vmcnt(0)" ::: "memory");
      slab_barrier<16>(flagB0, slab, (uint32_t)(t + 1), tid);
    }
  } else {
    // ================= LAYER 1 =================
    u16* ldsW = (u16*)pool;                              // [3][16][KP1_]
    u16 (*ldsX)[KP1_] = (u16(*)[KP1_])(pool + 99072);    // [16][KP1_]
    float (*h32b)[16] = (float(*)[16])(pool + 132096);   // [16][16]
    float (*xg32)[16] = (float(*)[16])(pool + 133120);   // [16][16]
    const int b2 = bid - 64;
    const int grp = b2 & 3;
    const int slab = b2 >> 2;          // 0..31
    const int j0 = slab * 16;
    const int gb = grp * 16;
    const int gcol = j0 + fr;

    for (int idx = tid; idx < 3 * 16 * 128; idx += 256) {
      int gate = idx >> 11;            // /2048
      int rem = idx & 2047;
      int cl = rem >> 7;
      int kc = (rem & 127) * 8;
      *(v8s*)&ldsW[((gate * 16) + cl) * KP1_ + kc] =
          *(const v8s*)(Wstk1 + ((size_t)(gate * H_) + (j0 + cl)) * 1024 + kc);
    }
    for (int i = tid; i < 16 * H_; i += 256) {
      int row = i >> 9, col = i & (H_ - 1);
      ldsX[row][512 + col] = f2bf(hs[((size_t)(gb + row) * 2 + 1) * H_ + col]);
    }
    for (int i = tid; i < 16 * 16; i += 256) {
      int row = i >> 4, c = i & 15;
      h32b[row][c] = hs[((size_t)(gb + row) * 2 + 1) * H_ + j0 + c];
    }
    __syncthreads();

    const float bzv = bz1[gcol], brv = br1[gcol], bgv = bg1[gcol];
    u16* h1_g = h1buf + (size_t)gb * H_;
    u16* hr1_g = hr1buf + (size_t)gb * H_;
    const u16* wZ = ldsW + ((size_t)(0 * 16) + fr) * KP1_;
    const u16* wR = ldsW + ((size_t)(1 * 16) + fr) * KP1_;
    const u16* wG = ldsW + ((size_t)(2 * 16) + fr) * KP1_;
    uint32_t* flagB0 = flags + 1024 + (size_t)grp * 16 * FPAD_;
    uint32_t* flagA1 = flags + 2048 + (size_t)grp * 32 * FPAD_;
    uint32_t* flagB1 = flags + 4096 + (size_t)grp * 32 * FPAD_;
    uint32_t* c1g    = flags + 6144 + (size_t)grp * 32 * FPAD_;
    float* hf1 = hfinal + (size_t)B_ * H_;

    float zv0 = 0.f, zv1 = 0.f, zv2 = 0.f, zv3 = 0.f;

    for (int t = 0; t < S_; ++t) {
      // wait for L0's h(t); own h1(t-1) readiness is implied by loop-end
      // flagB1 barrier
      if (tid < 16) pollge(flagB0 + tid * FPAD_, (uint32_t)(t + 1));
      __syncthreads();
      {
        const uint64_t* s0 =
            (const uint64_t*)(h0buf + ((size_t)(t & 1) * B_ + gb) * H_);
        uint64_t q0[8];
#pragma unroll
        for (int i = 0; i < 8; ++i) q0[i] = cload64(s0 + i * 256 + tid);
        if (t > 0) {
          const uint64_t* s1 = (const uint64_t*)h1_g;
          uint64_t q1[8];
#pragma unroll
          for (int i = 0; i < 8; ++i) q1[i] = cload64(s1 + i * 256 + tid);
#pragma unroll
          for (int i = 0; i < 8; ++i) {
            int d = i * 256 + tid;
            *(uint64_t*)&ldsX[d >> 7][512 + (d & 127) * 4] = q1[i];
          }
        }
#pragma unroll
        for (int i = 0; i < 8; ++i) {
          int d = i * 256 + tid;
          *(uint64_t*)&ldsX[d >> 7][(d & 127) * 4] = q0[i];
        }
      }
      __syncthreads();
      if (tid == 0) cstore32(&c1g[slab * FPAD_], (uint32_t)(t + 1));

      // ---- phase A: w0: z (K=1024), w1: r (K=1024) -> hr, w2: xg (K=512)
      if (w < 2) {
        const u16* wB = (w == 0) ? wZ : wR;
        v4f a0 = {0,0,0,0}, a1 = {0,0,0,0}, a2 = {0,0,0,0}, a3 = {0,0,0,0};
#pragma unroll
        for (int kk = 0; kk < 8; ++kk) {
          a0 = mfma16(*(const v8s*)&ldsX[fr][kk * 32 + kb],
                      *(const v8s*)(wB + kk * 32 + kb), a0);
          a1 = mfma16(*(const v8s*)&ldsX[fr][256 + kk * 32 + kb],
                      *(const v8s*)(wB + 256 + kk * 32 + kb), a1);
          a2 = mfma16(*(const v8s*)&ldsX[fr][512 + kk * 32 + kb],
                      *(const v8s*)(wB + 512 + kk * 32 + kb), a2);
          a3 = mfma16(*(const v8s*)&ldsX[fr][768 + kk * 32 + kb],
                      *(const v8s*)(wB + 768 + kk * 32 + kb), a3);
        }
        float pre[4];
#pragma unroll
        for (int j = 0; j < 4; ++j) {
          float s = a0[j] + a1[j] + a2[j] + a3[j] + ((w == 0) ? bzv : brv);
          pre[j] = 1.0f / (1.0f + __expf(-s));
        }
        if (w == 0) {
          zv0 = pre[0]; zv1 = pre[1]; zv2 = pre[2]; zv3 = pre[3];
        } else {
#pragma unroll
          for (int j = 0; j < 4; ++j) {
            float v = pre[j] * h32b[rb + j][fr];
            float o1 = __shfl_xor(v, 1);
            uint32_t c0 = f2bf(v), c1 = f2bf(o1);
            uint32_t pk = (fr & 1) ? (c1 | (c0 << 16)) : (c0 | (c1 << 16));
            uint32_t pk2 = __shfl_xor(pk, 2);
            if ((fr & 3) == 0)
              cstore64((uint64_t*)&hr1_g[(size_t)(rb + j) * H_ + gcol],
                       (uint64_t)pk | ((uint64_t)pk2 << 32));
          }
        }
      } else if (w == 2) {
        v4f a0 = {0,0,0,0}, a1 = {0,0,0,0};
#pragma unroll
        for (int kk = 0; kk < 8; ++kk) {
          a0 = mfma16(*(const v8s*)&ldsX[fr][kk * 32 + kb],
                      *(const v8s*)(wG + kk * 32 + kb), a0);
          a1 = mfma16(*(const v8s*)&ldsX[fr][256 + kk * 32 + kb],
                      *(const v8s*)(wG + 256 + kk * 32 + kb), a1);
        }
#pragma unroll
        for (int j = 0; j < 4; ++j) xg32[rb + j][fr] = a0[j] + a1[j];
      }
      asm volatile("s_waitcnt vmcnt(0)" ::: "memory");
      slab_barrier<32>(flagA1, slab, (uint32_t)(t + 1), tid);

      {  // stage hr into second half
        const uint64_t* sr = (const uint64_t*)hr1_g;
        uint64_t q[8];
#pragma unroll
        for (int i = 0; i < 8; ++i) q[i] = cload64(sr + i * 256 + tid);
#pragma unroll
        for (int i = 0; i < 8; ++i) {
          int d = i * 256 + tid;
          *(uint64_t*)&ldsX[d >> 7][512 + (d & 127) * 4] = q[i];
        }
        __syncthreads();
      }

      // ---- phase B: w0: g (hr half) + update + broadcast + seq ----
      if (w == 0) {
        v4f g0 = {0,0,0,0}, g1 = {0,0,0,0};
#pragma unroll
        for (int kk = 0; kk < 8; ++kk) {
          g0 = mfma16(*(const v8s*)&ldsX[fr][512 + kk * 32 + kb],
                      *(const v8s*)(wG + 512 + kk * 32 + kb), g0);
          g1 = mfma16(*(const v8s*)&ldsX[fr][768 + kk * 32 + kb],
                      *(const v8s*)(wG + 768 + kk * 32 + kb), g1);
        }
        float zv[4] = {zv0, zv1, zv2, zv3};
#pragma unroll
        for (int j = 0; j < 4; ++j) {
          int b = gb + rb + j;
          float gval = tanhf(g0[j] + g1[j] + xg32[rb + j][fr] + bgv);
          float hold = h32b[rb + j][fr];
          float hnew = zv[j] * hold + (1.0f - zv[j]) * gval;
          h32b[rb + j][fr] = hnew;
          uint32_t c0 = f2bf(hnew);
          float o1 = __shfl_xor(hnew, 1);
          uint32_t c1 = f2bf(o1);
          uint32_t pk = (fr & 1) ? (c1 | (c0 << 16)) : (c0 | (c1 << 16));
          uint32_t pk2 = __shfl_xor(pk, 2);
          if ((fr & 3) == 0) {
            uint64_t qv = (uint64_t)pk | ((uint64_t)pk2 << 32);
            cstore64((uint64_t*)&h1_g[(size_t)(rb + j) * H_ + gcol], qv);
            *(uint64_t*)&seqout[((size_t)b * S_ + t) * H_ + gcol] = qv;
          }
          if (t == S_ - 1) hf1[(size_t)b * H_ + gcol] = hnew;
        }
      }
      asm volatile("s_waitcnt vmcnt(0)" ::: "memory");
      slab_barrier<32>(flagB1, slab, (uint32_t)(t + 1), tid);
    }
  }
}

// ---------------------------------------------------------------- launch
extern "C" void kernel_launch(void* const* d_in, const int* in_sizes, int n_in,
                              void* d_out, int out_size, void* d_ws,
                              size_t ws_size, hipStream_t stream) {
  const float* input = (const float*)d_in[0];
  const float* hs = (const float*)d_in[1];
  const float* W_in[2][3] = {
      {(const float*)d_in[2], (const float*)d_in[5], (const float*)d_in[8]},
      {(const float*)d_in[11], (const float*)d_in[14], (const float*)d_in[17]}};
  const float* W_h[2][3] = {
      {(const float*)d_in[3], (const float*)d_in[6], (const float*)d_in[9]},
      {(const float*)d_in[12], (const float*)d_in[15], (const float*)d_in[18]}};
  const float* bias[2][3] = {
      {(const float*)d_in[4], (const float*)d_in[7], (const float*)d_in[10]},
      {(const float*)d_in[13], (const float*)d_in[16], (const float*)d_in[19]}};
  const float* Wo = (const float*)d_in[20];
  const float* bo = (const float*)d_in[21];
  float* out = (float*)d_out;

  // ---------------- workspace layout (peak ~207.5 MB) ----------------
  char* ws = (char*)d_ws;
  u16* xproj   = (u16*)(ws + 0);             // 201,326,592 B
  u16* wtin0   = (u16*)(ws + 201326592);     // [1536][256]   786,432 B
  u16* wth0    = (u16*)(ws + 202113024);     // [3][512][512] 1,572,864 B
  u16* wstk1   = (u16*)(ws + 203685888);     // [3][512][1024] 3,145,728 B
  u16* wot     = (u16*)(ws + 206831616);     // [256][512]    262,144 B
  u16* h0buf   = (u16*)(ws + 207093760);     // [2][64][512]  131,072 B
  u16* hr0buf  = (u16*)(ws + 207224832);     // [64][512]      65,536 B
  u16* h1buf   = (u16*)(ws + 207290368);     // [64][512]      65,536 B
  u16* hr1buf  = (u16*)(ws + 207355904);     // [64][512]      65,536 B
  uint32_t* flags = (uint32_t*)(ws + 207421440); // 8192 u32 = 32,768 B

  u16* inbf = (u16*)d_out;                   // 33.5 MB in d_out y-region
  u16* seq2 = xproj;                         // layer-1 seq aliases z-slice

  // 1. cast input to bf16 (into d_out y-region scratch)
  cast_input_kernel<<<2048, 256, 0, stream>>>(input, inbf, BS_ * IN_ / 4);

  // 2. pack weights: L0 separate, L1 stacked [Win; Wh] (K=1024)
  for (int g = 0; g < 3; ++g) {
    pack_transpose_k<<<256, 256, 0, stream>>>(
        W_in[0][g], wtin0 + (size_t)g * H_ * IN_, IN_, H_, IN_, 0);
    pack_transpose_k<<<256, 256, 0, stream>>>(
        W_h[0][g], wth0 + (size_t)g * H_ * H_, H_, H_, H_, 0);
    pack_transpose_k<<<256, 256, 0, stream>>>(
        W_in[1][g], wstk1 + (size_t)g * H_ * 1024, H_, H_, 1024, 0);
    pack_transpose_k<<<256, 256, 0, stream>>>(
        W_h[1][g], wstk1 + (size_t)g * H_ * 1024, H_, H_, 1024, 512);
  }
  pack_transpose_k<<<256, 256, 0, stream>>>(Wo, wot, H_, OUT_, H_, 0);

  // 3. layer-0 input projections for all timesteps: [BS] x [1536]
  gemm_kernel<<<dim3(24, 1024), 256, 0, stream>>>(
      inbf, wtin0, 1536, IN_, xproj, nullptr, nullptr, 0);

  // 4. pipelined two-layer scan (192 persistent WGs)
  hipMemsetAsync(flags, 0, 32768, stream);
  const size_t ysz = (size_t)BS_ * OUT_;
  float* hfin = out + ysz;
  gru_pipe_kernel<<<dim3(192), dim3(256), 0, stream>>>(
      xproj, wth0, wstk1, bias[0][0], bias[0][1], bias[0][2], bias[1][0],
      bias[1][1], bias[1][2], hs, h0buf, hr0buf, h1buf, hr1buf, seq2, hfin,
      flags);

  // 5. output projection: y = seq2 @ Wo + bo (overwrites inbf, dead by now)
  gemm_kernel<<<dim3(4, 1024), 256, 0, stream>>>(seq2, wot, OUT_, H_, nullptr,
                                                 out, bo, 1);
}